// Round 11
// baseline (128.397 us; speedup 1.0000x reference)
//
#include <hip/hip_runtime.h>
#include <math.h>

// Qnet: per-row tiny MLP + gumbel-sigmoid straight-through gates + 5 tiny experts.
//
// Round-10 post-mortem: r8 (VGPR64/8w)=123us, r10 (VGPR80/6w)=125us, r9
// (VGPR132/3w)=217us -> occupancy 6-8 waves/SIMD is sufficient; plateau is
// ISSUE COUNT (VALUBusy 55%, HBM 27%). This round: pack the row-pair's
// duplicated FMA stream into v_pk_fma_f32 / v_pk_max_f32 via
// ext_vector_type(2) (lane = row). ~380 paired FMA-class ops -> ~190
// packed issues; transcendentals (15/row) stay scalar. Memory layout
// identical to r10 (float4 x/out, float2 u/soft/hard; the row<->lane
// transpose is register naming only).
// Flag window |ep-t2e| < 1.05e-4*t2e per gate; flagged ROWS patched by the
// bit-exact CR-f32 numpy simulation (correctness authority).

constexpr float EPSF = 1e-8f;

typedef float v2f __attribute__((ext_vector_type(2)));

static __device__ __forceinline__ v2f s2(float s) { return (v2f){s, s}; }

__global__ __launch_bounds__(256) void qnet_main(
    const float* __restrict__ x,
    const float* __restrict__ u1,
    const float* __restrict__ u2,
    const float* __restrict__ fc1_w,    // [4][4]
    const float* __restrict__ fc1_b,    // [4]
    const float* __restrict__ picker_w, // [5][4]
    const float* __restrict__ picker_b, // [5]
    const float* __restrict__ ew1,      // [5][4][4]
    const float* __restrict__ eb1,      // [5][4]
    const float* __restrict__ ew2,      // [5][2][4]
    const float* __restrict__ eb2,      // [5][2]
    float* __restrict__ out_o,          // [B][2]
    float* __restrict__ hard_o,         // [B][5]
    float* __restrict__ soft_o,         // [B][5]
    unsigned* __restrict__ flag_cnt,    // d_ws[0]
    unsigned* __restrict__ flag_list,   // d_ws[1..]
    unsigned flag_cap)
{
    const unsigned t = blockIdx.x * blockDim.x + threadIdx.x;  // rows 2t, 2t+1

    const float4* x4  = reinterpret_cast<const float4*>(x);
    const float2* u12 = reinterpret_cast<const float2*>(u1);
    const float2* u22 = reinterpret_cast<const float2*>(u2);

    // x rows as pair-lanes
    const float4 xa = x4[2u * t + 0];
    const float4 xb = x4[2u * t + 1];
    v2f xp[4];
    xp[0] = (v2f){xa.x, xb.x}; xp[1] = (v2f){xa.y, xb.y};
    xp[2] = (v2f){xa.z, xb.z}; xp[3] = (v2f){xa.w, xb.w};

    // u loads (float2 chunks, then regroup per gate: lane = row)
    float2 l1[5], l2[5];
#pragma unroll
    for (int k = 0; k < 5; ++k) {
        l1[k] = u12[5u * t + k];
        l2[k] = u22[5u * t + k];
    }
    // u1p[c] = {u1[row0][c], u1[row1][c]}
    v2f u1p[5], u2p[5];
    u1p[0] = (v2f){l1[0].x, l1[2].y}; u1p[1] = (v2f){l1[0].y, l1[3].x};
    u1p[2] = (v2f){l1[1].x, l1[3].y}; u1p[3] = (v2f){l1[1].y, l1[4].x};
    u1p[4] = (v2f){l1[2].x, l1[4].y};
    u2p[0] = (v2f){l2[0].x, l2[2].y}; u2p[1] = (v2f){l2[0].y, l2[3].x};
    u2p[2] = (v2f){l2[1].x, l2[3].y}; u2p[3] = (v2f){l2[1].y, l2[4].x};
    u2p[4] = (v2f){l2[2].x, l2[4].y};

    // h = tanh(fc1(x)) — packed FMA, scalar transcendentals
    v2f h[4];
#pragma unroll
    for (int j = 0; j < 4; ++j) {
        v2f a = s2(fc1_b[j]);
#pragma unroll
        for (int i = 0; i < 4; ++i) a += xp[i] * s2(fc1_w[4 * j + i]);
        // tanh(a) = 2/(1+exp(-2a)) - 1
        const float ex = __expf(-2.0f * a.x);
        const float ey = __expf(-2.0f * a.y);
        h[j] = (v2f){fmaf(2.0f, __builtin_amdgcn_rcpf(1.0f + ex), -1.0f),
                     fmaf(2.0f, __builtin_amdgcn_rcpf(1.0f + ey), -1.0f)};
    }

    v2f o0 = s2(0.0f), o1 = s2(0.0f);
    v2f softp[5], hardp[5];
    v2f rowmin = s2(1e30f);

#pragma unroll
    for (int c = 0; c < 5; ++c) {
        v2f lg = s2(picker_b[c]);
#pragma unroll
        for (int j = 0; j < 4; ++j) lg += h[j] * s2(picker_w[4 * c + j]);

        // gumbel e-domain (scalar trans per lane)
        const v2f a1 = u1p[c] + s2(EPSF);
        const v2f a2 = u2p[c] + s2(EPSF);
        const v2f t1e = (v2f){-__logf(a1.x) + EPSF, -__logf(a1.y) + EPSF};
        const v2f t2e = (v2f){-__logf(a2.x) + EPSF, -__logf(a2.y) + EPSF};
        const v2f epv = (v2f){__expf(-lg.x), __expf(-lg.y)} * t1e;
        const v2f den = t2e + epv;
        const v2f sft = t2e * (v2f){__builtin_amdgcn_rcpf(den.x),
                                    __builtin_amdgcn_rcpf(den.y)};
        const v2f hrd = (v2f){(epv.x <= t2e.x) ? 1.0f : 0.0f,
                              (epv.y <= t2e.y) ? 1.0f : 0.0f};

        const v2f marg = __builtin_elementwise_abs(epv - t2e) - s2(1.05e-4f) * t2e;
        rowmin = __builtin_elementwise_min(rowmin, marg);

        softp[c] = sft;
        hardp[c] = hrd;

        // expert c: Linear(4,4)->ReLU->Linear(4,2)  (packed)
        v2f eh[4];
#pragma unroll
        for (int k = 0; k < 4; ++k) {
            v2f a = s2(eb1[4 * c + k]);
#pragma unroll
            for (int j = 0; j < 4; ++j) a += h[j] * s2(ew1[16 * c + 4 * k + j]);
            eh[k] = __builtin_elementwise_max(a, s2(0.0f));
        }
        v2f e0 = s2(eb2[2 * c + 0]);
        v2f e1 = s2(eb2[2 * c + 1]);
#pragma unroll
        for (int k = 0; k < 4; ++k) {
            e0 += eh[k] * s2(ew2[8 * c + 0 + k]);
            e1 += eh[k] * s2(ew2[8 * c + 4 + k]);
        }
        o0 += hrd * e0;
        o1 += hrd * e1;
    }

    // rare flags, one per row
    if (__builtin_expect(rowmin.x < 0.0f, 0)) {
        unsigned mask = 0;
#pragma unroll
        for (int c = 0; c < 5; ++c) mask |= (hardp[c].x != 0.0f) ? (1u << c) : 0u;
        const unsigned slot = atomicAdd(flag_cnt, 1u);
        if (slot < flag_cap) flag_list[slot] = ((2u * t + 0) << 5) | mask;
    }
    if (__builtin_expect(rowmin.y < 0.0f, 0)) {
        unsigned mask = 0;
#pragma unroll
        for (int c = 0; c < 5; ++c) mask |= (hardp[c].y != 0.0f) ? (1u << c) : 0u;
        const unsigned slot = atomicAdd(flag_cnt, 1u);
        if (slot < flag_cap) flag_list[slot] = ((2u * t + 1) << 5) | mask;
    }

    // stores: out float4, soft/hard 5x float2 (register transpose back)
    reinterpret_cast<float4*>(out_o)[t] = make_float4(o0.x, o1.x, o0.y, o1.y);
    float2* s2o = reinterpret_cast<float2*>(soft_o);
    float2* h2o = reinterpret_cast<float2*>(hard_o);
    s2o[5u * t + 0] = make_float2(softp[0].x, softp[1].x);
    s2o[5u * t + 1] = make_float2(softp[2].x, softp[3].x);
    s2o[5u * t + 2] = make_float2(softp[4].x, softp[0].y);
    s2o[5u * t + 3] = make_float2(softp[1].y, softp[2].y);
    s2o[5u * t + 4] = make_float2(softp[3].y, softp[4].y);
    h2o[5u * t + 0] = make_float2(hardp[0].x, hardp[1].x);
    h2o[5u * t + 1] = make_float2(hardp[2].x, hardp[3].x);
    h2o[5u * t + 2] = make_float2(hardp[4].x, hardp[0].y);
    h2o[5u * t + 3] = make_float2(hardp[1].y, hardp[2].y);
    h2o[5u * t + 4] = make_float2(hardp[3].y, hardp[4].y);
}

// ---- rare patch kernel: bit-exact CR-f32 numpy simulation (authority) ----
// One entry = one flagged ROW (row<<5 | fast-hard mask); recompute all 5 gates.
__global__ __launch_bounds__(256) void qnet_patch(
    const float* __restrict__ x,
    const float* __restrict__ u1,
    const float* __restrict__ u2,
    const float* __restrict__ fc1_w,
    const float* __restrict__ fc1_b,
    const float* __restrict__ picker_w,
    const float* __restrict__ picker_b,
    const float* __restrict__ ew1,
    const float* __restrict__ eb1,
    const float* __restrict__ ew2,
    const float* __restrict__ eb2,
    float* __restrict__ out_o,
    float* __restrict__ hard_o,
    float* __restrict__ soft_o,
    const unsigned* __restrict__ flag_cnt,
    const unsigned* __restrict__ flag_list,
    unsigned flag_cap)
{
    const unsigned n = min(flag_cnt[0], flag_cap);
    const unsigned stride = gridDim.x * blockDim.x;
    for (unsigned i = blockIdx.x * blockDim.x + threadIdx.x; i < n; i += stride) {
        const unsigned e = flag_list[i];
        const unsigned row = e >> 5;
        const unsigned fmask = e & 31u;

        const float4 xv = reinterpret_cast<const float4*>(x)[row];
        const float xr[4] = {xv.x, xv.y, xv.z, xv.w};

        float h32[4];
#pragma unroll
        for (int j = 0; j < 4; ++j) {
            float acc = 0.0f;
#pragma unroll
            for (int i2 = 0; i2 < 4; ++i2)
                acc = fmaf(xr[i2], fc1_w[4 * j + i2], acc);
            const float hpre = acc + fc1_b[j];
            h32[j] = (float)tanh((double)hpre);
        }

        float dout0 = 0.0f, dout1 = 0.0f;
#pragma unroll
        for (int c = 0; c < 5; ++c) {
            const unsigned idx5 = row * 5u + c;
            const float uu1 = u1[idx5];
            const float uu2 = u2[idx5];

            float lacc = 0.0f;
#pragma unroll
            for (int j = 0; j < 4; ++j)
                lacc = fmaf(h32[j], picker_w[4 * c + j], lacc);
            const float lg32 = lacc + picker_b[c];
            const float a1 = uu1 + EPSF;
            const float l1 = (float)log((double)a1);
            const float b1 = (-l1) + EPSF;
            const float g1s = -((float)log((double)b1));
            const float a2 = uu2 + EPSF;
            const float l2 = (float)log((double)a2);
            const float b2 = (-l2) + EPSF;
            const float g2s = -((float)log((double)b2));
            const float dd = g1s - g2s;
            const float z32 = lg32 + dd;
            const float e32 = (float)exp((double)(-z32));
            const float den = 1.0f + e32;
            const float s32 = 1.0f / den;
            const float crhard = (s32 >= 0.5f) ? 1.0f : 0.0f;
            const float fasthard = ((fmask >> c) & 1u) ? 1.0f : 0.0f;

            soft_o[idx5] = s32;
            hard_o[idx5] = crhard;

            if (crhard != fasthard) {
                float eh[4];
#pragma unroll
                for (int k = 0; k < 4; ++k) {
                    float a = eb1[4 * c + k];
#pragma unroll
                    for (int j = 0; j < 4; ++j) a += h32[j] * ew1[16 * c + 4 * k + j];
                    eh[k] = fmaxf(a, 0.0f);
                }
                float e0 = eb2[2 * c + 0];
                float e1 = eb2[2 * c + 1];
#pragma unroll
                for (int k = 0; k < 4; ++k) {
                    e0 += eh[k] * ew2[8 * c + 0 + k];
                    e1 += eh[k] * ew2[8 * c + 4 + k];
                }
                const float d = crhard - fasthard;   // +1 or -1
                dout0 += d * e0;
                dout1 += d * e1;
            }
        }
        if (dout0 != 0.0f) atomicAdd(&out_o[2u * row + 0], dout0);
        if (dout1 != 0.0f) atomicAdd(&out_o[2u * row + 1], dout1);
    }
}

extern "C" void kernel_launch(void* const* d_in, const int* in_sizes, int n_in,
                              void* d_out, int out_size, void* d_ws, size_t ws_size,
                              hipStream_t stream) {
    const float* x        = (const float*)d_in[0];
    const float* u1       = (const float*)d_in[1];
    const float* u2       = (const float*)d_in[2];
    const float* fc1_w    = (const float*)d_in[3];
    const float* fc1_b    = (const float*)d_in[4];
    const float* picker_w = (const float*)d_in[5];
    const float* picker_b = (const float*)d_in[6];
    const float* ew1      = (const float*)d_in[7];
    const float* eb1      = (const float*)d_in[8];
    const float* ew2      = (const float*)d_in[9];
    const float* eb2      = (const float*)d_in[10];

    const long long B = in_sizes[0] / 4;        // rows
    float* out  = (float*)d_out;                // [B][2]
    float* hard = out + (size_t)B * 2;          // [B][5]
    float* soft = hard + (size_t)B * 5;         // [B][5]

    unsigned* flag_cnt  = (unsigned*)d_ws;
    unsigned* flag_list = flag_cnt + 1;
    const unsigned flag_cap = (unsigned)(ws_size / 4 - 1);

    hipMemsetAsync(d_ws, 0, 4, stream);         // zero the counter (capturable)

    const int threads = 256;
    const long long nthreads = B / 2;           // 2 rows per thread
    const int blocks = (int)((nthreads + threads - 1) / threads);
    qnet_main<<<blocks, threads, 0, stream>>>(
        x, u1, u2, fc1_w, fc1_b, picker_w, picker_b,
        ew1, eb1, ew2, eb2, out, hard, soft,
        flag_cnt, flag_list, flag_cap);

    qnet_patch<<<128, 256, 0, stream>>>(
        x, u1, u2, fc1_w, fc1_b, picker_w, picker_b,
        ew1, eb1, ew2, eb2, out, hard, soft,
        flag_cnt, flag_list, flag_cap);
}